// Round 7
// baseline (327.819 us; speedup 1.0000x reference)
//
#include <hip/hip_runtime.h>

#define VN 49152
#define DEG 20
#define NB 2
#define MROWS (NB * VN)   // 98304 rows

static constexpr float BN_EPS = 1e-5f;

typedef short bf16x8 __attribute__((ext_vector_type(8)));
typedef float floatx4 __attribute__((ext_vector_type(4)));

__device__ __forceinline__ unsigned short f2bf(float f) {
  unsigned int u = __builtin_bit_cast(unsigned int, f);
  u += 0x7FFFu + ((u >> 16) & 1u);            // RNE
  return (unsigned short)(u >> 16);
}
__device__ __forceinline__ float bf2f(unsigned short h) {
  unsigned int u = ((unsigned int)h) << 16;
  return __builtin_bit_cast(float, u);
}
__device__ __forceinline__ float bflo(unsigned int u) {
  return __builtin_bit_cast(float, u << 16);
}
__device__ __forceinline__ float bfhi(unsigned int u) {
  return __builtin_bit_cast(float, u & 0xFFFF0000u);
}
__device__ __forceinline__ unsigned int packbf(float a, float b) {
  return (unsigned int)f2bf(a) | ((unsigned int)f2bf(b) << 16);
}
__device__ __forceinline__ void bfunpack8(const uint4& d, float* f) {
  f[0] = bflo(d.x); f[1] = bfhi(d.x); f[2] = bflo(d.y); f[3] = bfhi(d.y);
  f[4] = bflo(d.z); f[5] = bfhi(d.z); f[6] = bflo(d.w); f[7] = bfhi(d.w);
}

// Feature planes (64-ch) stored SWIZZLED as 4 sub-planes [batch][chalf][VN][32]
// addr(b,v,ch) = ((b*2 + ch/32)*VN + v)*32 + ch%32. A combo = 3.15MB -> L2.

// ======================= GEMM1: t1 = x @ W1 + b1 ===========================
#define LDA1 136
__global__ __launch_bounds__(256) void gemm1(const float* __restrict__ X,
    const float* __restrict__ W, const float* __restrict__ bias,
    unsigned short* __restrict__ Y, float* __restrict__ st) {
  __shared__ unsigned short As[128 * LDA1];
  __shared__ unsigned short Bs[64 * LDA1];
  __shared__ float sred[128];
  int t = threadIdx.x;
  int row0 = blockIdx.x * 128;
  if (t < 128) sred[t] = 0.f;
  const float* Xt = X + (size_t)row0 * 128;
  #pragma unroll
  for (int c = 0; c < 16; ++c) {
    int f4i = c * 256 + t;
    int row = f4i >> 5, k = (f4i & 31) * 4;
    float4 v = *(const float4*)(Xt + row * 128 + k);
    *(uint2*)(&As[row * LDA1 + k]) = make_uint2(packbf(v.x, v.y), packbf(v.z, v.w));
  }
  #pragma unroll
  for (int c = 0; c < 32; ++c) {
    int f = c * 256 + t;
    int k = f >> 6, n = f & 63;
    Bs[n * LDA1 + k] = f2bf(W[f]);
  }
  __syncthreads();
  int l = t & 63, wv = t >> 6;
  int lr = l & 15, q = l >> 4;
  int m0 = wv * 32;
  floatx4 acc[2][4];
  #pragma unroll
  for (int mi = 0; mi < 2; ++mi)
    #pragma unroll
    for (int ni = 0; ni < 4; ++ni) acc[mi][ni] = (floatx4)(0.f);
  #pragma unroll
  for (int ks = 0; ks < 128; ks += 32) {
    bf16x8 af[2], bfr[4];
    #pragma unroll
    for (int mi = 0; mi < 2; ++mi)
      af[mi] = *(const bf16x8*)(&As[(m0 + mi * 16 + lr) * LDA1 + ks + q * 8]);
    #pragma unroll
    for (int ni = 0; ni < 4; ++ni)
      bfr[ni] = *(const bf16x8*)(&Bs[(ni * 16 + lr) * LDA1 + ks + q * 8]);
    #pragma unroll
    for (int mi = 0; mi < 2; ++mi)
      #pragma unroll
      for (int ni = 0; ni < 4; ++ni)
        acc[mi][ni] = __builtin_amdgcn_mfma_f32_16x16x32_bf16(af[mi], bfr[ni], acc[mi][ni], 0, 0, 0);
  }
  int b = (row0 >= VN) ? 1 : 0;
  int vbase = row0 - b * VN + m0;
  #pragma unroll
  for (int ni = 0; ni < 4; ++ni) {
    int col = ni * 16 + lr;
    float bv = bias[col];
    size_t sub = (size_t)(b * 2 + (col >> 5)) * VN;
    float s = 0.f, s2 = 0.f;
    #pragma unroll
    for (int mi = 0; mi < 2; ++mi)
      #pragma unroll
      for (int r = 0; r < 4; ++r) {
        float y = acc[mi][ni][r] + bv;
        s += y; s2 += y * y;
        int v = vbase + mi * 16 + q * 4 + r;
        Y[(sub + v) * 32 + (col & 31)] = f2bf(y);
      }
    atomicAdd(&sred[col], s);
    atomicAdd(&sred[64 + col], s2);
  }
  __syncthreads();
  if (t < 128) atomicAdd(&st[t], sred[t]);
}

// -------- spmm1: x1 = L * relu(bn1(t1)); bn applied on the fly -------------
__global__ __launch_bounds__(256) void spmm1(const unsigned short* __restrict__ T1,
    const int* __restrict__ cols, const float* __restrict__ vals,
    const float* __restrict__ st1, const float* __restrict__ g1,
    const float* __restrict__ be1, unsigned short* __restrict__ X1out) {
  __shared__ float scS[64], shS[64];
  int t = threadIdx.x;
  if (t < 64) {
    float mean = st1[t] * (1.f / MROWS);
    float var = st1[64 + t] * (1.f / MROWS) - mean * mean;
    float sc = g1[t] * rsqrtf(var + BN_EPS);
    scS[t] = sc; shS[t] = be1[t] - mean * sc;
  }
  __syncthreads();
  int g = blockIdx.x;
  int combo = (g & 7) >> 1;
  int rg = ((g >> 3) << 1) | (g & 1);
  int wv = t >> 6, lane = t & 63;
  int v = rg * 64 + wv * 16 + (lane >> 2);
  int ch0 = (lane & 3) * 8;
  int chg = (combo & 1) * 32 + ch0;
  float sc8[8], sh8[8];
  #pragma unroll
  for (int j = 0; j < 8; ++j) { sc8[j] = scS[chg + j]; sh8[j] = shS[chg + j]; }
  const unsigned short* __restrict__ plane = T1 + (size_t)combo * VN * 32;
  int4  c4[5];
  float4 w4[5];
  const int4*   __restrict__ cp4 = (const int4*)(cols + VN + v * DEG);
  const float4* __restrict__ vp4 = (const float4*)(vals + VN + v * DEG);
  #pragma unroll
  for (int j = 0; j < 5; ++j) { c4[j] = cp4[j]; w4[j] = vp4[j]; }
  float a[8];
  {
    float w0 = vals[v];
    uint4 d = *(const uint4*)(plane + (size_t)v * 32 + ch0);
    float f[8]; bfunpack8(d, f);
    #pragma unroll
    for (int j = 0; j < 8; ++j) {
      float h = fmaf(f[j], sc8[j], sh8[j]); h = h > 0.f ? h : 0.f;
      a[j] = w0 * h;
    }
  }
  #pragma unroll
  for (int jj = 0; jj < 5; ++jj) {
    const int cj[4] = {c4[jj].x, c4[jj].y, c4[jj].z, c4[jj].w};
    const float wj[4] = {w4[jj].x, w4[jj].y, w4[jj].z, w4[jj].w};
    #pragma unroll
    for (int e = 0; e < 4; ++e) {
      uint4 d = *(const uint4*)(plane + (size_t)cj[e] * 32 + ch0);
      float f[8]; bfunpack8(d, f);
      float w = wj[e];
      #pragma unroll
      for (int j = 0; j < 8; ++j) {
        float h = fmaf(f[j], sc8[j], sh8[j]); h = h > 0.f ? h : 0.f;
        a[j] = fmaf(h, w, a[j]);
      }
    }
  }
  uint4 o;
  o.x = packbf(a[0], a[1]); o.y = packbf(a[2], a[3]);
  o.z = packbf(a[4], a[5]); o.w = packbf(a[6], a[7]);
  *(uint4*)(X1out + (size_t)combo * VN * 32 + (size_t)v * 32 + ch0) = o;
}

// ===== GEMM2: t2 = h1@W2[0] + x1@W2[1] + x2@W2[2] + b2 =====================
// h1 = relu(bn1(t1)) recomputed in staging; x2 = 2*(L x1) - h1 computed
// in-kernel (band-local gather) — never materialized. Term order: 2,0,1
// so MFMA accumulators aren't live during the heavy gather phase.
#define LDA2 72
__global__ __launch_bounds__(256) void gemm2(const unsigned short* __restrict__ T1,
    const unsigned short* __restrict__ X1, const int* __restrict__ cols,
    const float* __restrict__ vals, const float* __restrict__ st1,
    const float* __restrict__ g1, const float* __restrict__ be1,
    const float* __restrict__ W, const float* __restrict__ bias,
    unsigned short* __restrict__ Y, float* __restrict__ st2) {
  __shared__ unsigned short As[128 * LDA2];
  __shared__ unsigned short Bs[64 * LDA2];
  __shared__ float sred[128];
  __shared__ float scS[64], shS[64];
  int t = threadIdx.x;
  int row0 = blockIdx.x * 128;
  int b = (row0 >= VN) ? 1 : 0;
  int b2 = b * 2;
  int vb0 = row0 - b * VN;
  if (t < 128) sred[t] = 0.f;
  if (t < 64) {
    float mean = st1[t] * (1.f / MROWS);
    float var = st1[64 + t] * (1.f / MROWS) - mean * mean;
    float sc = g1[t] * rsqrtf(var + BN_EPS);
    scS[t] = sc; shS[t] = be1[t] - mean * sc;
  }
  __syncthreads();
  int l = t & 63, wv = t >> 6;
  int lr = l & 15, q = l >> 4;
  int m0 = wv * 32;
  floatx4 acc[2][4];
  #pragma unroll
  for (int mi = 0; mi < 2; ++mi)
    #pragma unroll
    for (int ni = 0; ni < 4; ++ni) acc[mi][ni] = (floatx4)(0.f);

  auto stage_b = [&](const float* Wt) {
    #pragma unroll
    for (int c = 0; c < 16; ++c) {
      int f = c * 256 + t;
      int k = f >> 6, n = f & 63;
      Bs[n * LDA2 + k] = f2bf(Wt[f]);
    }
  };
  auto mfma_tile = [&]() {
    #pragma unroll
    for (int ks = 0; ks < 64; ks += 32) {
      bf16x8 af[2], bfr[4];
      #pragma unroll
      for (int mi = 0; mi < 2; ++mi)
        af[mi] = *(const bf16x8*)(&As[(m0 + mi * 16 + lr) * LDA2 + ks + q * 8]);
      #pragma unroll
      for (int ni = 0; ni < 4; ++ni)
        bfr[ni] = *(const bf16x8*)(&Bs[(ni * 16 + lr) * LDA2 + ks + q * 8]);
      #pragma unroll
      for (int mi = 0; mi < 2; ++mi)
        #pragma unroll
        for (int ni = 0; ni < 4; ++ni)
          acc[mi][ni] = __builtin_amdgcn_mfma_f32_16x16x32_bf16(af[mi], bfr[ni], acc[mi][ni], 0, 0, 0);
    }
  };

  // ---- term 2: As = x2 = 2*(L x1) - h1 for this band (gather) ----
  #pragma unroll 1
  for (int it = 0; it < 4; ++it) {
    int u = it * 256 + t;
    int row = u >> 3;
    int ch0 = (u & 7) * 8;
    int hc = ch0 >> 5;
    int cin = ch0 & 31;
    int v = vb0 + row;
    const unsigned short* __restrict__ pl = X1 + ((size_t)(b2 + hc) * VN) * 32 + cin;
    const unsigned short* __restrict__ tp = T1 + ((size_t)(b2 + hc) * VN) * 32 + cin;
    float sc8[8], sh8[8];
    #pragma unroll
    for (int j = 0; j < 8; ++j) { sc8[j] = scS[ch0 + j]; sh8[j] = shS[ch0 + j]; }
    float h[8];
    {
      uint4 tv = *(const uint4*)(tp + (size_t)v * 32);
      float f[8]; bfunpack8(tv, f);
      #pragma unroll
      for (int j = 0; j < 8; ++j) {
        float y = fmaf(f[j], sc8[j], sh8[j]);
        h[j] = y > 0.f ? y : 0.f;
      }
    }
    float a[8];
    {
      float w0 = vals[v];
      uint4 d = *(const uint4*)(pl + (size_t)v * 32);
      float f[8]; bfunpack8(d, f);
      #pragma unroll
      for (int j = 0; j < 8; ++j) a[j] = w0 * f[j];
    }
    int4  c4[5];
    float4 w4[5];
    const int4*   __restrict__ cp4 = (const int4*)(cols + VN + v * DEG);
    const float4* __restrict__ vp4 = (const float4*)(vals + VN + v * DEG);
    #pragma unroll
    for (int j = 0; j < 5; ++j) { c4[j] = cp4[j]; w4[j] = vp4[j]; }
    #pragma unroll
    for (int jj = 0; jj < 5; ++jj) {
      const int cj[4] = {c4[jj].x, c4[jj].y, c4[jj].z, c4[jj].w};
      const float wj[4] = {w4[jj].x, w4[jj].y, w4[jj].z, w4[jj].w};
      #pragma unroll
      for (int e = 0; e < 4; ++e) {
        uint4 d = *(const uint4*)(pl + (size_t)cj[e] * 32);
        float f[8]; bfunpack8(d, f);
        float w = wj[e];
        #pragma unroll
        for (int j = 0; j < 8; ++j) a[j] = fmaf(f[j], w, a[j]);
      }
    }
    uint4 o;
    o.x = packbf(2.f * a[0] - h[0], 2.f * a[1] - h[1]);
    o.y = packbf(2.f * a[2] - h[2], 2.f * a[3] - h[3]);
    o.z = packbf(2.f * a[4] - h[4], 2.f * a[5] - h[5]);
    o.w = packbf(2.f * a[6] - h[6], 2.f * a[7] - h[7]);
    *(uint4*)(&As[row * LDA2 + ch0]) = o;
  }
  stage_b(W + 2 * 64 * 64);
  __syncthreads();
  mfma_tile();
  __syncthreads();

  // ---- term 0: As = h1 = relu(bn1(t1)) band ----
  #pragma unroll
  for (int c8 = 0; c8 < 8; ++c8) {
    int i = c8 * 256 + t;
    int row = i >> 4, k = (i & 15) * 4;
    const unsigned short* src = T1 + ((size_t)(b2 + (k >> 5)) * VN + vb0 + row) * 32 + (k & 31);
    uint2 rawv = *(const uint2*)src;
    float y0 = fmaf(bflo(rawv.x), scS[k + 0], shS[k + 0]);
    float y1 = fmaf(bfhi(rawv.x), scS[k + 1], shS[k + 1]);
    float y2 = fmaf(bflo(rawv.y), scS[k + 2], shS[k + 2]);
    float y3 = fmaf(bfhi(rawv.y), scS[k + 3], shS[k + 3]);
    y0 = y0 > 0.f ? y0 : 0.f; y1 = y1 > 0.f ? y1 : 0.f;
    y2 = y2 > 0.f ? y2 : 0.f; y3 = y3 > 0.f ? y3 : 0.f;
    *(uint2*)(&As[row * LDA2 + k]) = make_uint2(packbf(y0, y1), packbf(y2, y3));
  }
  stage_b(W);
  __syncthreads();
  mfma_tile();
  __syncthreads();

  // ---- term 1: As = x1 band (raw) ----
  #pragma unroll
  for (int c8 = 0; c8 < 8; ++c8) {
    int i = c8 * 256 + t;
    int row = i >> 4, k = (i & 15) * 4;
    const unsigned short* src = X1 + ((size_t)(b2 + (k >> 5)) * VN + vb0 + row) * 32 + (k & 31);
    *(uint2*)(&As[row * LDA2 + k]) = *(const uint2*)src;
  }
  stage_b(W + 64 * 64);
  __syncthreads();
  mfma_tile();

  int vbase = vb0 + m0;
  #pragma unroll
  for (int ni = 0; ni < 4; ++ni) {
    int col = ni * 16 + lr;
    float bv = bias[col];
    size_t sub = (size_t)(b2 + (col >> 5)) * VN;
    float s = 0.f, s2 = 0.f;
    #pragma unroll
    for (int mi = 0; mi < 2; ++mi)
      #pragma unroll
      for (int r = 0; r < 4; ++r) {
        float y = acc[mi][ni][r] + bv;
        s += y; s2 += y * y;
        int v = vbase + mi * 16 + q * 4 + r;
        Y[(sub + v) * 32 + (col & 31)] = f2bf(y);
      }
    atomicAdd(&sred[col], s);
    atomicAdd(&sred[64 + col], s2);
  }
  __syncthreads();
  if (t < 128) atomicAdd(&st2[t], sred[t]);
}

// ====== GEMM3: t3 = h2 @ W3 + b3 (full N=128 per block, coalesced out) =====
#define LDC3 136   // out-staging stride in ushorts (=17 uint4, 16B aligned)
__global__ __launch_bounds__(256) void gemm3(const unsigned short* __restrict__ X,
    const float* __restrict__ W, const float* __restrict__ bias,
    const float* __restrict__ st2, const float* __restrict__ gamma,
    const float* __restrict__ beta, unsigned short* __restrict__ Y,
    float* __restrict__ st3) {
  __shared__ unsigned short smem[18432];   // As[128*72] | Bs[128*72]; reused as OutS[128*136]
  __shared__ float sred[256];
  __shared__ float scS[64], shS[64];
  unsigned short* As = smem;
  unsigned short* Bs = smem + 128 * LDA2;
  int t = threadIdx.x;
  int row0 = blockIdx.x * 128;
  int b = (row0 >= VN) ? 1 : 0;
  int b2 = b * 2;
  int vb0 = row0 - b * VN;
  sred[t] = 0.f;
  if (t < 64) {
    float mean = st2[t] * (1.f / MROWS);
    float var = st2[64 + t] * (1.f / MROWS) - mean * mean;
    float sc = gamma[t] * rsqrtf(var + BN_EPS);
    scS[t] = sc; shS[t] = beta[t] - mean * sc;
  }
  __syncthreads();
  // A stage: h2 = relu(bn2(t2))
  #pragma unroll
  for (int c8 = 0; c8 < 8; ++c8) {
    int i = c8 * 256 + t;
    int row = i >> 4, k = (i & 15) * 4;
    const unsigned short* src = X + ((size_t)(b2 + (k >> 5)) * VN + vb0 + row) * 32 + (k & 31);
    uint2 rawv = *(const uint2*)src;
    float y0 = fmaf(bflo(rawv.x), scS[k + 0], shS[k + 0]);
    float y1 = fmaf(bfhi(rawv.x), scS[k + 1], shS[k + 1]);
    float y2 = fmaf(bflo(rawv.y), scS[k + 2], shS[k + 2]);
    float y3 = fmaf(bfhi(rawv.y), scS[k + 3], shS[k + 3]);
    y0 = y0 > 0.f ? y0 : 0.f; y1 = y1 > 0.f ? y1 : 0.f;
    y2 = y2 > 0.f ? y2 : 0.f; y3 = y3 > 0.f ? y3 : 0.f;
    *(uint2*)(&As[row * LDA2 + k]) = make_uint2(packbf(y0, y1), packbf(y2, y3));
  }
  // B stage: all 128 cols, B^T [n][k]
  #pragma unroll
  for (int c = 0; c < 32; ++c) {
    int f = c * 256 + t;
    int k = f >> 7, n = f & 127;
    Bs[n * LDA2 + k] = f2bf(W[k * 128 + n]);
  }
  __syncthreads();
  int l = t & 63, wv = t >> 6;
  int lr = l & 15, q = l >> 4;
  int m0 = wv * 32;
  floatx4 acc[2][8];
  #pragma unroll
  for (int mi = 0; mi < 2; ++mi)
    #pragma unroll
    for (int ni = 0; ni < 8; ++ni) acc[mi][ni] = (floatx4)(0.f);
  #pragma unroll
  for (int ks = 0; ks < 64; ks += 32) {
    bf16x8 af[2], bfr[8];
    #pragma unroll
    for (int mi = 0; mi < 2; ++mi)
      af[mi] = *(const bf16x8*)(&As[(m0 + mi * 16 + lr) * LDA2 + ks + q * 8]);
    #pragma unroll
    for (int ni = 0; ni < 8; ++ni)
      bfr[ni] = *(const bf16x8*)(&Bs[(ni * 16 + lr) * LDA2 + ks + q * 8]);
    #pragma unroll
    for (int mi = 0; mi < 2; ++mi)
      #pragma unroll
      for (int ni = 0; ni < 8; ++ni)
        acc[mi][ni] = __builtin_amdgcn_mfma_f32_16x16x32_bf16(af[mi], bfr[ni], acc[mi][ni], 0, 0, 0);
  }
  __syncthreads();   // As/Bs reads done; smem becomes OutS
  unsigned short* OutS = smem;
  #pragma unroll
  for (int ni = 0; ni < 8; ++ni) {
    int col = ni * 16 + lr;
    float bv = bias[col];
    float s = 0.f, s2 = 0.f;
    #pragma unroll
    for (int mi = 0; mi < 2; ++mi)
      #pragma unroll
      for (int r = 0; r < 4; ++r) {
        float y = acc[mi][ni][r] + bv;
        s += y; s2 += y * y;
        int row = m0 + mi * 16 + q * 4 + r;
        OutS[row * LDC3 + col] = f2bf(y);
      }
    atomicAdd(&sred[col], s);
    atomicAdd(&sred[128 + col], s2);
  }
  __syncthreads();
  atomicAdd(&st3[t], sred[t]);
  #pragma unroll
  for (int c = 0; c < 8; ++c) {
    int idx = c * 256 + t;
    int row = idx >> 4, seg = idx & 15;
    *(uint4*)(Y + ((size_t)(row0 + row)) * 128 + seg * 8) =
        *(const uint4*)(&OutS[row * LDC3 + seg * 8]);
  }
}

// --------- final: out = relu(bn3(t3)) fp32; bn3 finalized inline -----------
__global__ __launch_bounds__(256) void bn_final(const unsigned short* __restrict__ T,
    float* __restrict__ Y, const float* __restrict__ st3,
    const float* __restrict__ gamma, const float* __restrict__ beta) {
  __shared__ float scS[128], shS[128];
  int t = threadIdx.x;
  if (t < 128) {
    float mean = st3[t] * (1.f / MROWS);
    float var = st3[128 + t] * (1.f / MROWS) - mean * mean;
    float sc = gamma[t] * rsqrtf(var + BN_EPS);
    scS[t] = sc;
    shS[t] = beta[t] - mean * sc;
  }
  __syncthreads();
  size_t i4 = ((size_t)blockIdx.x * 256 + t) * 4;
  int c0 = (int)(i4 & 127);
  ushort4 tv = *(const ushort4*)(T + i4);
  unsigned short sv[4] = {tv.x, tv.y, tv.z, tv.w};
  float ov[4];
  #pragma unroll
  for (int j = 0; j < 4; ++j) {
    int c = c0 + j;
    float y = fmaf(bf2f(sv[j]), scS[c], shS[c]);
    ov[j] = y > 0.f ? y : 0.f;
  }
  *(float4*)(Y + i4) = make_float4(ov[0], ov[1], ov[2], ov[3]);
}

extern "C" void kernel_launch(void* const* d_in, const int* in_sizes, int n_in,
                              void* d_out, int out_size, void* d_ws, size_t ws_size,
                              hipStream_t stream) {
  const float* x    = (const float*)d_in[0];
  const int*   cols = (const int*)  d_in[2];
  const float* vals = (const float*)d_in[3];
  const float* W1   = (const float*)d_in[4];
  const float* b1   = (const float*)d_in[5];
  const float* g1   = (const float*)d_in[6];
  const float* be1  = (const float*)d_in[7];
  const float* W2   = (const float*)d_in[8];
  const float* b2   = (const float*)d_in[9];
  const float* g2   = (const float*)d_in[10];
  const float* be2  = (const float*)d_in[11];
  const float* W3   = (const float*)d_in[12];
  const float* b3   = (const float*)d_in[13];
  const float* g3   = (const float*)d_in[14];
  const float* be3  = (const float*)d_in[15];
  float* out = (float*)d_out;

  const size_t PL = (size_t)MROWS * 64;          // plane elements
  unsigned short* P0 = (unsigned short*)d_ws;    // t1, then t2 (in-place)
  unsigned short* P1 = P0 + PL;                  // x1
  unsigned short* P2 = P1 + PL;                  // t3 [MROWS,128]
  float* st1 = (float*)(P2 + 2 * PL);            // 128
  float* st2 = st1 + 128;                        // 128
  float* st3 = st2 + 128;                        // 256

  hipMemsetAsync(st1, 0, 512 * sizeof(float), stream);

  dim3 blk(256);
  int rowb = MROWS / 128;                        // 768
  int spmm_blocks = 3072;                        // 64 rows x 4 combos
  int ap128_blocks = (int)(PL * 2 / 4 / 256);    // 12288

  // Layer 1 (stats via atomics; bn1 applied by consumers)
  gemm1<<<rowb, blk, 0, stream>>>(x, W1, b1, P0, st1);

  // Layer 2: spmm1 gathers raw t1 with bn+relu on the fly; gemm2 computes
  // x2 internally (spmm2 + bn_h1 kernels eliminated)
  spmm1<<<spmm_blocks, blk, 0, stream>>>(P0, cols, vals, st1, g1, be1, P1);
  gemm2<<<rowb, blk, 0, stream>>>(P0, P1, cols, vals, st1, g1, be1,
                                  W2, b2, P0, st2);   // t2 -> P0 (band-local)

  // Layer 3
  gemm3<<<rowb, blk, 0, stream>>>(P0, W3, b3, st2, g2, be2, P2, st3);
  bn_final<<<ap128_blocks, blk, 0, stream>>>(P2, out, st3, g3, be3);
}

// Round 8
// 303.913 us; speedup vs baseline: 1.0787x; 1.0787x over previous
//
#include <hip/hip_runtime.h>

#define VN 49152
#define DEG 20
#define NB 2
#define MROWS (NB * VN)   // 98304 rows

static constexpr float BN_EPS = 1e-5f;

typedef short bf16x8 __attribute__((ext_vector_type(8)));
typedef float floatx4 __attribute__((ext_vector_type(4)));

__device__ __forceinline__ unsigned short f2bf(float f) {
  unsigned int u = __builtin_bit_cast(unsigned int, f);
  u += 0x7FFFu + ((u >> 16) & 1u);            // RNE
  return (unsigned short)(u >> 16);
}
__device__ __forceinline__ float bf2f(unsigned short h) {
  unsigned int u = ((unsigned int)h) << 16;
  return __builtin_bit_cast(float, u);
}
__device__ __forceinline__ float bflo(unsigned int u) {
  return __builtin_bit_cast(float, u << 16);
}
__device__ __forceinline__ float bfhi(unsigned int u) {
  return __builtin_bit_cast(float, u & 0xFFFF0000u);
}
__device__ __forceinline__ unsigned int packbf(float a, float b) {
  return (unsigned int)f2bf(a) | ((unsigned int)f2bf(b) << 16);
}
__device__ __forceinline__ void bfunpack8(const uint4& d, float* f) {
  f[0] = bflo(d.x); f[1] = bfhi(d.x); f[2] = bflo(d.y); f[3] = bfhi(d.y);
  f[4] = bflo(d.z); f[5] = bfhi(d.z); f[6] = bflo(d.w); f[7] = bfhi(d.w);
}

// Feature planes (64-ch) stored SWIZZLED as 4 sub-planes [batch][chalf][VN][32]
// addr(b,v,ch) = ((b*2 + ch/32)*VN + v)*32 + ch%32. A combo = 3.15MB -> L2.
// spmm kernels pin combo via blockIdx%8 (R7 lesson: breaking this costs 6x fetch).

// ======================= GEMM1: t1 = x @ W1 + b1 ===========================
#define LDA1 136
__global__ __launch_bounds__(256) void gemm1(const float* __restrict__ X,
    const float* __restrict__ W, const float* __restrict__ bias,
    unsigned short* __restrict__ Y, float* __restrict__ st) {
  __shared__ unsigned short As[128 * LDA1];
  __shared__ unsigned short Bs[64 * LDA1];
  __shared__ float sred[128];
  int t = threadIdx.x;
  int row0 = blockIdx.x * 128;
  if (t < 128) sred[t] = 0.f;
  const float* Xt = X + (size_t)row0 * 128;
  #pragma unroll
  for (int c = 0; c < 16; ++c) {
    int f4i = c * 256 + t;
    int row = f4i >> 5, k = (f4i & 31) * 4;
    float4 v = *(const float4*)(Xt + row * 128 + k);
    *(uint2*)(&As[row * LDA1 + k]) = make_uint2(packbf(v.x, v.y), packbf(v.z, v.w));
  }
  #pragma unroll
  for (int c = 0; c < 32; ++c) {
    int f = c * 256 + t;
    int k = f >> 6, n = f & 63;
    Bs[n * LDA1 + k] = f2bf(W[f]);
  }
  __syncthreads();
  int l = t & 63, wv = t >> 6;
  int lr = l & 15, q = l >> 4;
  int m0 = wv * 32;
  floatx4 acc[2][4];
  #pragma unroll
  for (int mi = 0; mi < 2; ++mi)
    #pragma unroll
    for (int ni = 0; ni < 4; ++ni) acc[mi][ni] = (floatx4)(0.f);
  #pragma unroll
  for (int ks = 0; ks < 128; ks += 32) {
    bf16x8 af[2], bfr[4];
    #pragma unroll
    for (int mi = 0; mi < 2; ++mi)
      af[mi] = *(const bf16x8*)(&As[(m0 + mi * 16 + lr) * LDA1 + ks + q * 8]);
    #pragma unroll
    for (int ni = 0; ni < 4; ++ni)
      bfr[ni] = *(const bf16x8*)(&Bs[(ni * 16 + lr) * LDA1 + ks + q * 8]);
    #pragma unroll
    for (int mi = 0; mi < 2; ++mi)
      #pragma unroll
      for (int ni = 0; ni < 4; ++ni)
        acc[mi][ni] = __builtin_amdgcn_mfma_f32_16x16x32_bf16(af[mi], bfr[ni], acc[mi][ni], 0, 0, 0);
  }
  int b = (row0 >= VN) ? 1 : 0;
  int vbase = row0 - b * VN + m0;
  #pragma unroll
  for (int ni = 0; ni < 4; ++ni) {
    int col = ni * 16 + lr;
    float bv = bias[col];
    size_t sub = (size_t)(b * 2 + (col >> 5)) * VN;
    float s = 0.f, s2 = 0.f;
    #pragma unroll
    for (int mi = 0; mi < 2; ++mi)
      #pragma unroll
      for (int r = 0; r < 4; ++r) {
        float y = acc[mi][ni][r] + bv;
        s += y; s2 += y * y;
        int v = vbase + mi * 16 + q * 4 + r;
        Y[(sub + v) * 32 + (col & 31)] = f2bf(y);
      }
    atomicAdd(&sred[col], s);
    atomicAdd(&sred[64 + col], s2);
  }
  __syncthreads();
  if (t < 128) atomicAdd(&st[t], sred[t]);
}

// -------- spmm1: x1 = L * relu(bn1(t1)); bn applied on the fly -------------
__global__ __launch_bounds__(256) void spmm1(const unsigned short* __restrict__ T1,
    const int* __restrict__ cols, const float* __restrict__ vals,
    const float* __restrict__ st1, const float* __restrict__ g1,
    const float* __restrict__ be1, unsigned short* __restrict__ X1out) {
  __shared__ float scS[64], shS[64];
  int t = threadIdx.x;
  if (t < 64) {
    float mean = st1[t] * (1.f / MROWS);
    float var = st1[64 + t] * (1.f / MROWS) - mean * mean;
    float sc = g1[t] * rsqrtf(var + BN_EPS);
    scS[t] = sc; shS[t] = be1[t] - mean * sc;
  }
  __syncthreads();
  int g = blockIdx.x;
  int combo = (g & 7) >> 1;
  int rg = ((g >> 3) << 1) | (g & 1);
  int wv = t >> 6, lane = t & 63;
  int v = rg * 64 + wv * 16 + (lane >> 2);
  int ch0 = (lane & 3) * 8;
  int chg = (combo & 1) * 32 + ch0;
  float sc8[8], sh8[8];
  #pragma unroll
  for (int j = 0; j < 8; ++j) { sc8[j] = scS[chg + j]; sh8[j] = shS[chg + j]; }
  const unsigned short* __restrict__ plane = T1 + (size_t)combo * VN * 32;
  int4  c4[5];
  float4 w4[5];
  const int4*   __restrict__ cp4 = (const int4*)(cols + VN + v * DEG);
  const float4* __restrict__ vp4 = (const float4*)(vals + VN + v * DEG);
  #pragma unroll
  for (int j = 0; j < 5; ++j) { c4[j] = cp4[j]; w4[j] = vp4[j]; }
  float a[8];
  {
    float w0 = vals[v];
    uint4 d = *(const uint4*)(plane + (size_t)v * 32 + ch0);
    float f[8]; bfunpack8(d, f);
    #pragma unroll
    for (int j = 0; j < 8; ++j) {
      float h = fmaf(f[j], sc8[j], sh8[j]); h = h > 0.f ? h : 0.f;
      a[j] = w0 * h;
    }
  }
  #pragma unroll
  for (int jj = 0; jj < 5; ++jj) {
    const int cj[4] = {c4[jj].x, c4[jj].y, c4[jj].z, c4[jj].w};
    const float wj[4] = {w4[jj].x, w4[jj].y, w4[jj].z, w4[jj].w};
    #pragma unroll
    for (int e = 0; e < 4; ++e) {
      uint4 d = *(const uint4*)(plane + (size_t)cj[e] * 32 + ch0);
      float f[8]; bfunpack8(d, f);
      float w = wj[e];
      #pragma unroll
      for (int j = 0; j < 8; ++j) {
        float h = fmaf(f[j], sc8[j], sh8[j]); h = h > 0.f ? h : 0.f;
        a[j] = fmaf(h, w, a[j]);
      }
    }
  }
  uint4 o;
  o.x = packbf(a[0], a[1]); o.y = packbf(a[2], a[3]);
  o.z = packbf(a[4], a[5]); o.w = packbf(a[6], a[7]);
  *(uint4*)(X1out + (size_t)combo * VN * 32 + (size_t)v * 32 + ch0) = o;
}

// ------ spmm2: x2 = 2*(L x1) - h1; h1 = relu(bn1(t1)) recomputed inline ----
__global__ __launch_bounds__(256) void spmm2(const unsigned short* __restrict__ X1,
    const unsigned short* __restrict__ T1, const int* __restrict__ cols,
    const float* __restrict__ vals, const float* __restrict__ st1,
    const float* __restrict__ g1, const float* __restrict__ be1,
    unsigned short* __restrict__ X2out) {
  __shared__ float scS[64], shS[64];
  int t = threadIdx.x;
  if (t < 64) {
    float mean = st1[t] * (1.f / MROWS);
    float var = st1[64 + t] * (1.f / MROWS) - mean * mean;
    float sc = g1[t] * rsqrtf(var + BN_EPS);
    scS[t] = sc; shS[t] = be1[t] - mean * sc;
  }
  __syncthreads();
  int g = blockIdx.x;
  int combo = (g & 7) >> 1;
  int rg = ((g >> 3) << 1) | (g & 1);
  int wv = t >> 6, lane = t & 63;
  int v = rg * 64 + wv * 16 + (lane >> 2);
  int ch0 = (lane & 3) * 8;
  int chg = (combo & 1) * 32 + ch0;
  const size_t pbase = (size_t)combo * VN * 32;
  const size_t myoff = pbase + (size_t)v * 32 + ch0;
  const unsigned short* __restrict__ plane = X1 + pbase;
  int4  c4[5];
  float4 w4[5];
  const int4*   __restrict__ cp4 = (const int4*)(cols + VN + v * DEG);
  const float4* __restrict__ vp4 = (const float4*)(vals + VN + v * DEG);
  #pragma unroll
  for (int j = 0; j < 5; ++j) { c4[j] = cp4[j]; w4[j] = vp4[j]; }
  float a[8];
  {
    float w0 = vals[v];
    uint4 d = *(const uint4*)(X1 + myoff);
    float f[8]; bfunpack8(d, f);
    #pragma unroll
    for (int j = 0; j < 8; ++j) a[j] = w0 * f[j];
  }
  #pragma unroll
  for (int jj = 0; jj < 5; ++jj) {
    const int cj[4] = {c4[jj].x, c4[jj].y, c4[jj].z, c4[jj].w};
    const float wj[4] = {w4[jj].x, w4[jj].y, w4[jj].z, w4[jj].w};
    #pragma unroll
    for (int e = 0; e < 4; ++e) {
      uint4 d = *(const uint4*)(plane + (size_t)cj[e] * 32 + ch0);
      float f[8]; bfunpack8(d, f);
      float w = wj[e];
      #pragma unroll
      for (int j = 0; j < 8; ++j) a[j] = fmaf(f[j], w, a[j]);
    }
  }
  // h1 inline from t1
  uint4 tv = *(const uint4*)(T1 + myoff);
  float f[8]; bfunpack8(tv, f);
  float h[8];
  #pragma unroll
  for (int j = 0; j < 8; ++j) {
    float y = fmaf(f[j], scS[chg + j], shS[chg + j]);
    h[j] = y > 0.f ? y : 0.f;
  }
  uint4 o;
  o.x = packbf(2.f * a[0] - h[0], 2.f * a[1] - h[1]);
  o.y = packbf(2.f * a[2] - h[2], 2.f * a[3] - h[3]);
  o.z = packbf(2.f * a[4] - h[4], 2.f * a[5] - h[5]);
  o.w = packbf(2.f * a[6] - h[6], 2.f * a[7] - h[7]);
  *(uint4*)(X2out + myoff) = o;
}

// ===== GEMM2: t2 = h1@W2[0] + x1@W2[1] + x2@W2[2] + b2 =====================
// h1 = relu(bn1(t1)) recomputed during term-0 A-staging (band-local reads).
#define LDA2 72
__global__ __launch_bounds__(256) void gemm2(const unsigned short* __restrict__ T1,
    const unsigned short* __restrict__ X1, const unsigned short* __restrict__ X2,
    const float* __restrict__ st1, const float* __restrict__ g1,
    const float* __restrict__ be1, const float* __restrict__ W,
    const float* __restrict__ bias, unsigned short* __restrict__ Y,
    float* __restrict__ st2) {
  __shared__ unsigned short As[128 * LDA2];
  __shared__ unsigned short Bs[64 * LDA2];
  __shared__ float sred[128];
  __shared__ float scS[64], shS[64];
  int t = threadIdx.x;
  int row0 = blockIdx.x * 128;
  int b = (row0 >= VN) ? 1 : 0;
  int b2 = b * 2;
  int vb0 = row0 - b * VN;
  if (t < 128) sred[t] = 0.f;
  if (t < 64) {
    float mean = st1[t] * (1.f / MROWS);
    float var = st1[64 + t] * (1.f / MROWS) - mean * mean;
    float sc = g1[t] * rsqrtf(var + BN_EPS);
    scS[t] = sc; shS[t] = be1[t] - mean * sc;
  }
  __syncthreads();
  int l = t & 63, wv = t >> 6;
  int lr = l & 15, q = l >> 4;
  int m0 = wv * 32;
  floatx4 acc[2][4];
  #pragma unroll
  for (int mi = 0; mi < 2; ++mi)
    #pragma unroll
    for (int ni = 0; ni < 4; ++ni) acc[mi][ni] = (floatx4)(0.f);

  auto stage_b = [&](const float* Wt) {
    #pragma unroll
    for (int c = 0; c < 16; ++c) {
      int f = c * 256 + t;
      int k = f >> 6, n = f & 63;
      Bs[n * LDA2 + k] = f2bf(Wt[f]);
    }
  };
  auto mfma_tile = [&]() {
    #pragma unroll
    for (int ks = 0; ks < 64; ks += 32) {
      bf16x8 af[2], bfr[4];
      #pragma unroll
      for (int mi = 0; mi < 2; ++mi)
        af[mi] = *(const bf16x8*)(&As[(m0 + mi * 16 + lr) * LDA2 + ks + q * 8]);
      #pragma unroll
      for (int ni = 0; ni < 4; ++ni)
        bfr[ni] = *(const bf16x8*)(&Bs[(ni * 16 + lr) * LDA2 + ks + q * 8]);
      #pragma unroll
      for (int mi = 0; mi < 2; ++mi)
        #pragma unroll
        for (int ni = 0; ni < 4; ++ni)
          acc[mi][ni] = __builtin_amdgcn_mfma_f32_16x16x32_bf16(af[mi], bfr[ni], acc[mi][ni], 0, 0, 0);
    }
  };

  // ---- term 0: As = h1 = relu(bn1(t1)) band ----
  #pragma unroll
  for (int c8 = 0; c8 < 8; ++c8) {
    int i = c8 * 256 + t;
    int row = i >> 4, k = (i & 15) * 4;
    const unsigned short* src = T1 + ((size_t)(b2 + (k >> 5)) * VN + vb0 + row) * 32 + (k & 31);
    uint2 rawv = *(const uint2*)src;
    float y0 = fmaf(bflo(rawv.x), scS[k + 0], shS[k + 0]);
    float y1 = fmaf(bfhi(rawv.x), scS[k + 1], shS[k + 1]);
    float y2 = fmaf(bflo(rawv.y), scS[k + 2], shS[k + 2]);
    float y3 = fmaf(bfhi(rawv.y), scS[k + 3], shS[k + 3]);
    y0 = y0 > 0.f ? y0 : 0.f; y1 = y1 > 0.f ? y1 : 0.f;
    y2 = y2 > 0.f ? y2 : 0.f; y3 = y3 > 0.f ? y3 : 0.f;
    *(uint2*)(&As[row * LDA2 + k]) = make_uint2(packbf(y0, y1), packbf(y2, y3));
  }
  stage_b(W);
  __syncthreads();
  mfma_tile();
  __syncthreads();

  // ---- term 1: As = x1 band (raw) ----
  #pragma unroll
  for (int c8 = 0; c8 < 8; ++c8) {
    int i = c8 * 256 + t;
    int row = i >> 4, k = (i & 15) * 4;
    const unsigned short* src = X1 + ((size_t)(b2 + (k >> 5)) * VN + vb0 + row) * 32 + (k & 31);
    *(uint2*)(&As[row * LDA2 + k]) = *(const uint2*)src;
  }
  stage_b(W + 64 * 64);
  __syncthreads();
  mfma_tile();
  __syncthreads();

  // ---- term 2: As = x2 band (raw) ----
  #pragma unroll
  for (int c8 = 0; c8 < 8; ++c8) {
    int i = c8 * 256 + t;
    int row = i >> 4, k = (i & 15) * 4;
    const unsigned short* src = X2 + ((size_t)(b2 + (k >> 5)) * VN + vb0 + row) * 32 + (k & 31);
    *(uint2*)(&As[row * LDA2 + k]) = *(const uint2*)src;
  }
  stage_b(W + 2 * 64 * 64);
  __syncthreads();
  mfma_tile();

  int vbase = vb0 + m0;
  #pragma unroll
  for (int ni = 0; ni < 4; ++ni) {
    int col = ni * 16 + lr;
    float bv = bias[col];
    size_t sub = (size_t)(b2 + (col >> 5)) * VN;
    float s = 0.f, s2 = 0.f;
    #pragma unroll
    for (int mi = 0; mi < 2; ++mi)
      #pragma unroll
      for (int r = 0; r < 4; ++r) {
        float y = acc[mi][ni][r] + bv;
        s += y; s2 += y * y;
        int v = vbase + mi * 16 + q * 4 + r;
        Y[(sub + v) * 32 + (col & 31)] = f2bf(y);
      }
    atomicAdd(&sred[col], s);
    atomicAdd(&sred[64 + col], s2);
  }
  __syncthreads();
  if (t < 128) atomicAdd(&st2[t], sred[t]);
}

// ====== GEMM3: t3 = h2 @ W3 + b3 (full N=128 per block, coalesced out) =====
#define LDC3 136   // out-staging stride in ushorts (16B aligned segments)
__global__ __launch_bounds__(256) void gemm3(const unsigned short* __restrict__ X,
    const float* __restrict__ W, const float* __restrict__ bias,
    const float* __restrict__ st2, const float* __restrict__ gamma,
    const float* __restrict__ beta, unsigned short* __restrict__ Y,
    float* __restrict__ st3) {
  __shared__ unsigned short smem[18432];   // As[128*72] | Bs[128*72]; reused as OutS[128*136]
  __shared__ float sred[256];
  __shared__ float scS[64], shS[64];
  unsigned short* As = smem;
  unsigned short* Bs = smem + 128 * LDA2;
  int t = threadIdx.x;
  int row0 = blockIdx.x * 128;
  int b = (row0 >= VN) ? 1 : 0;
  int b2 = b * 2;
  int vb0 = row0 - b * VN;
  sred[t] = 0.f;
  if (t < 64) {
    float mean = st2[t] * (1.f / MROWS);
    float var = st2[64 + t] * (1.f / MROWS) - mean * mean;
    float sc = gamma[t] * rsqrtf(var + BN_EPS);
    scS[t] = sc; shS[t] = beta[t] - mean * sc;
  }
  __syncthreads();
  // A stage: h2 = relu(bn2(t2))
  #pragma unroll
  for (int c8 = 0; c8 < 8; ++c8) {
    int i = c8 * 256 + t;
    int row = i >> 4, k = (i & 15) * 4;
    const unsigned short* src = X + ((size_t)(b2 + (k >> 5)) * VN + vb0 + row) * 32 + (k & 31);
    uint2 rawv = *(const uint2*)src;
    float y0 = fmaf(bflo(rawv.x), scS[k + 0], shS[k + 0]);
    float y1 = fmaf(bfhi(rawv.x), scS[k + 1], shS[k + 1]);
    float y2 = fmaf(bflo(rawv.y), scS[k + 2], shS[k + 2]);
    float y3 = fmaf(bfhi(rawv.y), scS[k + 3], shS[k + 3]);
    y0 = y0 > 0.f ? y0 : 0.f; y1 = y1 > 0.f ? y1 : 0.f;
    y2 = y2 > 0.f ? y2 : 0.f; y3 = y3 > 0.f ? y3 : 0.f;
    *(uint2*)(&As[row * LDA2 + k]) = make_uint2(packbf(y0, y1), packbf(y2, y3));
  }
  // B stage: all 128 cols, B^T [n][k]
  #pragma unroll
  for (int c = 0; c < 32; ++c) {
    int f = c * 256 + t;
    int k = f >> 7, n = f & 127;
    Bs[n * LDA2 + k] = f2bf(W[k * 128 + n]);
  }
  __syncthreads();
  int l = t & 63, wv = t >> 6;
  int lr = l & 15, q = l >> 4;
  int m0 = wv * 32;
  floatx4 acc[2][8];
  #pragma unroll
  for (int mi = 0; mi < 2; ++mi)
    #pragma unroll
    for (int ni = 0; ni < 8; ++ni) acc[mi][ni] = (floatx4)(0.f);
  #pragma unroll
  for (int ks = 0; ks < 64; ks += 32) {
    bf16x8 af[2], bfr[8];
    #pragma unroll
    for (int mi = 0; mi < 2; ++mi)
      af[mi] = *(const bf16x8*)(&As[(m0 + mi * 16 + lr) * LDA2 + ks + q * 8]);
    #pragma unroll
    for (int ni = 0; ni < 8; ++ni)
      bfr[ni] = *(const bf16x8*)(&Bs[(ni * 16 + lr) * LDA2 + ks + q * 8]);
    #pragma unroll
    for (int mi = 0; mi < 2; ++mi)
      #pragma unroll
      for (int ni = 0; ni < 8; ++ni)
        acc[mi][ni] = __builtin_amdgcn_mfma_f32_16x16x32_bf16(af[mi], bfr[ni], acc[mi][ni], 0, 0, 0);
  }
  __syncthreads();   // As/Bs reads done; smem becomes OutS
  unsigned short* OutS = smem;
  #pragma unroll
  for (int ni = 0; ni < 8; ++ni) {
    int col = ni * 16 + lr;
    float bv = bias[col];
    float s = 0.f, s2 = 0.f;
    #pragma unroll
    for (int mi = 0; mi < 2; ++mi)
      #pragma unroll
      for (int r = 0; r < 4; ++r) {
        float y = acc[mi][ni][r] + bv;
        s += y; s2 += y * y;
        int row = m0 + mi * 16 + q * 4 + r;
        OutS[row * LDC3 + col] = f2bf(y);
      }
    atomicAdd(&sred[col], s);
    atomicAdd(&sred[128 + col], s2);
  }
  __syncthreads();
  atomicAdd(&st3[t], sred[t]);
  #pragma unroll
  for (int c = 0; c < 8; ++c) {
    int idx = c * 256 + t;
    int row = idx >> 4, seg = idx & 15;
    *(uint4*)(Y + ((size_t)(row0 + row)) * 128 + seg * 8) =
        *(const uint4*)(&OutS[row * LDC3 + seg * 8]);
  }
}

// --------- final: out = relu(bn3(t3)) fp32; bn3 finalized inline -----------
__global__ __launch_bounds__(256) void bn_final(const unsigned short* __restrict__ T,
    float* __restrict__ Y, const float* __restrict__ st3,
    const float* __restrict__ gamma, const float* __restrict__ beta) {
  __shared__ float scS[128], shS[128];
  int t = threadIdx.x;
  if (t < 128) {
    float mean = st3[t] * (1.f / MROWS);
    float var = st3[128 + t] * (1.f / MROWS) - mean * mean;
    float sc = gamma[t] * rsqrtf(var + BN_EPS);
    scS[t] = sc;
    shS[t] = beta[t] - mean * sc;
  }
  __syncthreads();
  size_t i4 = ((size_t)blockIdx.x * 256 + t) * 4;
  int c0 = (int)(i4 & 127);
  ushort4 tv = *(const ushort4*)(T + i4);
  unsigned short sv[4] = {tv.x, tv.y, tv.z, tv.w};
  float ov[4];
  #pragma unroll
  for (int j = 0; j < 4; ++j) {
    int c = c0 + j;
    float y = fmaf(bf2f(sv[j]), scS[c], shS[c]);
    ov[j] = y > 0.f ? y : 0.f;
  }
  *(float4*)(Y + i4) = make_float4(ov[0], ov[1], ov[2], ov[3]);
}

extern "C" void kernel_launch(void* const* d_in, const int* in_sizes, int n_in,
                              void* d_out, int out_size, void* d_ws, size_t ws_size,
                              hipStream_t stream) {
  const float* x    = (const float*)d_in[0];
  const int*   cols = (const int*)  d_in[2];
  const float* vals = (const float*)d_in[3];
  const float* W1   = (const float*)d_in[4];
  const float* b1   = (const float*)d_in[5];
  const float* g1   = (const float*)d_in[6];
  const float* be1  = (const float*)d_in[7];
  const float* W2   = (const float*)d_in[8];
  const float* b2   = (const float*)d_in[9];
  const float* g2   = (const float*)d_in[10];
  const float* be2  = (const float*)d_in[11];
  const float* W3   = (const float*)d_in[12];
  const float* b3   = (const float*)d_in[13];
  const float* g3   = (const float*)d_in[14];
  const float* be3  = (const float*)d_in[15];
  float* out = (float*)d_out;

  const size_t PL = (size_t)MROWS * 64;          // plane elements
  unsigned short* P0 = (unsigned short*)d_ws;    // t1, then t2 (band-local in-place)
  unsigned short* P1 = P0 + PL;                  // x1
  unsigned short* P2 = P1 + PL;                  // x2
  unsigned short* P3 = P2 + PL;                  // t3 [MROWS,128]
  float* st1 = (float*)(P3 + 2 * PL);            // 128
  float* st2 = st1 + 128;                        // 128
  float* st3 = st2 + 128;                        // 256

  hipMemsetAsync(st1, 0, 512 * sizeof(float), stream);

  dim3 blk(256);
  int rowb = MROWS / 128;                        // 768
  int spmm_blocks = 3072;                        // 64 rows x 4 combos
  int ap128_blocks = (int)(PL * 2 / 4 / 256);    // 12288

  // Layer 1 (stats via atomics; bn1 applied by consumers)
  gemm1<<<rowb, blk, 0, stream>>>(x, W1, b1, P0, st1);

  // Layer 2: standalone combo-pinned spmm kernels (R7 lesson), no bn_h1 pass
  spmm1<<<spmm_blocks, blk, 0, stream>>>(P0, cols, vals, st1, g1, be1, P1);
  spmm2<<<spmm_blocks, blk, 0, stream>>>(P1, P0, cols, vals, st1, g1, be1, P2);
  gemm2<<<rowb, blk, 0, stream>>>(P0, P1, P2, st1, g1, be1, W2, b2, P0, st2);

  // Layer 3
  gemm3<<<rowb, blk, 0, stream>>>(P0, W3, b3, st2, g2, be2, P3, st3);
  bn_final<<<ap128_blocks, blk, 0, stream>>>(P3, out, st3, g3, be3);
}

// Round 9
// 295.217 us; speedup vs baseline: 1.1104x; 1.0295x over previous
//
#include <hip/hip_runtime.h>

#define VN 49152
#define DEG 20
#define NB 2
#define MROWS (NB * VN)   // 98304 rows

static constexpr float BN_EPS = 1e-5f;

typedef short bf16x8 __attribute__((ext_vector_type(8)));
typedef float floatx4 __attribute__((ext_vector_type(4)));

__device__ __forceinline__ unsigned short f2bf(float f) {
  unsigned int u = __builtin_bit_cast(unsigned int, f);
  u += 0x7FFFu + ((u >> 16) & 1u);            // RNE
  return (unsigned short)(u >> 16);
}
__device__ __forceinline__ float bf2f(unsigned short h) {
  unsigned int u = ((unsigned int)h) << 16;
  return __builtin_bit_cast(float, u);
}
__device__ __forceinline__ float bflo(unsigned int u) {
  return __builtin_bit_cast(float, u << 16);
}
__device__ __forceinline__ float bfhi(unsigned int u) {
  return __builtin_bit_cast(float, u & 0xFFFF0000u);
}
__device__ __forceinline__ unsigned int packbf(float a, float b) {
  return (unsigned int)f2bf(a) | ((unsigned int)f2bf(b) << 16);
}
__device__ __forceinline__ void bfunpack8(const uint4& d, float* f) {
  f[0] = bflo(d.x); f[1] = bfhi(d.x); f[2] = bflo(d.y); f[3] = bfhi(d.y);
  f[4] = bflo(d.z); f[5] = bfhi(d.z); f[6] = bflo(d.w); f[7] = bfhi(d.w);
}

// Feature planes (64-ch) stored SWIZZLED as 4 sub-planes [batch][chalf][VN][32]
// addr(b,v,ch) = ((b*2 + ch/32)*VN + v)*32 + ch%32. A combo = 3.15MB -> L2.
// spmm kernels pin combo via blockIdx%8 (R7 lesson: breaking this costs 6x fetch).
// R8 lesson: barrier-serial GEMM blocks at 3 blocks/CU are latency-bound with
// everything idle -> GEMMs now stage only B in LDS (1 barrier) and each wave
// streams row-tiles with A-fragments loaded DIRECTLY from global
// (A[m=lane&15][k=quad*8+j] == per-lane uint4 from the swizzled plane).

// ======================= GEMM1: t1 = x @ W1 + b1 ===========================
// A direct from fp32 X (row-major [MROWS,128]); B (W1) in LDS.
#define LDB1 136
__global__ __launch_bounds__(256) void gemm1(const float* __restrict__ X,
    const float* __restrict__ W, const float* __restrict__ bias,
    unsigned short* __restrict__ Y, float* __restrict__ st) {
  __shared__ unsigned short Bs[64 * LDB1];     // B^T [n=64][k=128]
  __shared__ float sred[128];
  int t = threadIdx.x;
  int row0 = blockIdx.x * 128;
  int b = (row0 >= VN) ? 1 : 0;
  int b2 = b * 2;
  int vb0 = row0 - b * VN;
  if (t < 128) sred[t] = 0.f;
  #pragma unroll
  for (int c = 0; c < 32; ++c) {
    int f = c * 256 + t;                       // 8192 = 128*64
    int k = f >> 6, n = f & 63;
    Bs[n * LDB1 + k] = f2bf(W[f]);
  }
  __syncthreads();
  int lane = t & 63, wv = t >> 6;
  int lr = lane & 15, q = lane >> 4;
  float bv4[4];
  #pragma unroll
  for (int nt = 0; nt < 4; ++nt) bv4[nt] = bias[nt * 16 + lr];
  float s4[4] = {0.f, 0.f, 0.f, 0.f}, s24[4] = {0.f, 0.f, 0.f, 0.f};
  #pragma unroll
  for (int tile = 0; tile < 2; ++tile) {
    int vrow = row0 + wv * 32 + tile * 16 + lr;
    bf16x8 af[4];
    #pragma unroll
    for (int kh = 0; kh < 4; ++kh) {
      const float* xp = X + (size_t)vrow * 128 + kh * 32 + q * 8;
      float4 a0 = *(const float4*)xp;
      float4 a1 = *(const float4*)(xp + 4);
      uint4 u = make_uint4(packbf(a0.x, a0.y), packbf(a0.z, a0.w),
                           packbf(a1.x, a1.y), packbf(a1.z, a1.w));
      af[kh] = __builtin_bit_cast(bf16x8, u);
    }
    floatx4 acc[4];
    #pragma unroll
    for (int nt = 0; nt < 4; ++nt) acc[nt] = (floatx4)(0.f);
    #pragma unroll
    for (int kh = 0; kh < 4; ++kh)
      #pragma unroll
      for (int nt = 0; nt < 4; ++nt) {
        bf16x8 bfr = *(const bf16x8*)(&Bs[(nt * 16 + lr) * LDB1 + kh * 32 + q * 8]);
        acc[nt] = __builtin_amdgcn_mfma_f32_16x16x32_bf16(af[kh], bfr, acc[nt], 0, 0, 0);
      }
    int vbase = vb0 + wv * 32 + tile * 16 + q * 4;
    #pragma unroll
    for (int nt = 0; nt < 4; ++nt) {
      int col = nt * 16 + lr;
      size_t sub = (size_t)(b2 + (col >> 5)) * VN;
      #pragma unroll
      for (int r = 0; r < 4; ++r) {
        float y = acc[nt][r] + bv4[nt];
        s4[nt] += y; s24[nt] += y * y;
        Y[(sub + vbase + r) * 32 + (col & 31)] = f2bf(y);
      }
    }
  }
  #pragma unroll
  for (int nt = 0; nt < 4; ++nt) {
    int col = nt * 16 + lr;
    atomicAdd(&sred[col], s4[nt]);
    atomicAdd(&sred[64 + col], s24[nt]);
  }
  __syncthreads();
  if (t < 128) atomicAdd(&st[t], sred[t]);
}

// -------- spmm1: x1 = L * relu(bn1(t1)); bn applied on the fly -------------
__global__ __launch_bounds__(256) void spmm1(const unsigned short* __restrict__ T1,
    const int* __restrict__ cols, const float* __restrict__ vals,
    const float* __restrict__ st1, const float* __restrict__ g1,
    const float* __restrict__ be1, unsigned short* __restrict__ X1out) {
  __shared__ float scS[64], shS[64];
  int t = threadIdx.x;
  if (t < 64) {
    float mean = st1[t] * (1.f / MROWS);
    float var = st1[64 + t] * (1.f / MROWS) - mean * mean;
    float sc = g1[t] * rsqrtf(var + BN_EPS);
    scS[t] = sc; shS[t] = be1[t] - mean * sc;
  }
  __syncthreads();
  int g = blockIdx.x;
  int combo = (g & 7) >> 1;
  int rg = ((g >> 3) << 1) | (g & 1);
  int wv = t >> 6, lane = t & 63;
  int v = rg * 64 + wv * 16 + (lane >> 2);
  int ch0 = (lane & 3) * 8;
  int chg = (combo & 1) * 32 + ch0;
  float sc8[8], sh8[8];
  #pragma unroll
  for (int j = 0; j < 8; ++j) { sc8[j] = scS[chg + j]; sh8[j] = shS[chg + j]; }
  const unsigned short* __restrict__ plane = T1 + (size_t)combo * VN * 32;
  int4  c4[5];
  float4 w4[5];
  const int4*   __restrict__ cp4 = (const int4*)(cols + VN + v * DEG);
  const float4* __restrict__ vp4 = (const float4*)(vals + VN + v * DEG);
  #pragma unroll
  for (int j = 0; j < 5; ++j) { c4[j] = cp4[j]; w4[j] = vp4[j]; }
  float a[8];
  {
    float w0 = vals[v];
    uint4 d = *(const uint4*)(plane + (size_t)v * 32 + ch0);
    float f[8]; bfunpack8(d, f);
    #pragma unroll
    for (int j = 0; j < 8; ++j) {
      float h = fmaf(f[j], sc8[j], sh8[j]); h = h > 0.f ? h : 0.f;
      a[j] = w0 * h;
    }
  }
  #pragma unroll
  for (int jj = 0; jj < 5; ++jj) {
    const int cj[4] = {c4[jj].x, c4[jj].y, c4[jj].z, c4[jj].w};
    const float wj[4] = {w4[jj].x, w4[jj].y, w4[jj].z, w4[jj].w};
    #pragma unroll
    for (int e = 0; e < 4; ++e) {
      uint4 d = *(const uint4*)(plane + (size_t)cj[e] * 32 + ch0);
      float f[8]; bfunpack8(d, f);
      float w = wj[e];
      #pragma unroll
      for (int j = 0; j < 8; ++j) {
        float h = fmaf(f[j], sc8[j], sh8[j]); h = h > 0.f ? h : 0.f;
        a[j] = fmaf(h, w, a[j]);
      }
    }
  }
  uint4 o;
  o.x = packbf(a[0], a[1]); o.y = packbf(a[2], a[3]);
  o.z = packbf(a[4], a[5]); o.w = packbf(a[6], a[7]);
  *(uint4*)(X1out + (size_t)combo * VN * 32 + (size_t)v * 32 + ch0) = o;
}

// ------ spmm2: x2 = 2*(L x1) - h1; h1 = relu(bn1(t1)) recomputed inline ----
__global__ __launch_bounds__(256) void spmm2(const unsigned short* __restrict__ X1,
    const unsigned short* __restrict__ T1, const int* __restrict__ cols,
    const float* __restrict__ vals, const float* __restrict__ st1,
    const float* __restrict__ g1, const float* __restrict__ be1,
    unsigned short* __restrict__ X2out) {
  __shared__ float scS[64], shS[64];
  int t = threadIdx.x;
  if (t < 64) {
    float mean = st1[t] * (1.f / MROWS);
    float var = st1[64 + t] * (1.f / MROWS) - mean * mean;
    float sc = g1[t] * rsqrtf(var + BN_EPS);
    scS[t] = sc; shS[t] = be1[t] - mean * sc;
  }
  __syncthreads();
  int g = blockIdx.x;
  int combo = (g & 7) >> 1;
  int rg = ((g >> 3) << 1) | (g & 1);
  int wv = t >> 6, lane = t & 63;
  int v = rg * 64 + wv * 16 + (lane >> 2);
  int ch0 = (lane & 3) * 8;
  int chg = (combo & 1) * 32 + ch0;
  const size_t pbase = (size_t)combo * VN * 32;
  const size_t myoff = pbase + (size_t)v * 32 + ch0;
  const unsigned short* __restrict__ plane = X1 + pbase;
  int4  c4[5];
  float4 w4[5];
  const int4*   __restrict__ cp4 = (const int4*)(cols + VN + v * DEG);
  const float4* __restrict__ vp4 = (const float4*)(vals + VN + v * DEG);
  #pragma unroll
  for (int j = 0; j < 5; ++j) { c4[j] = cp4[j]; w4[j] = vp4[j]; }
  float a[8];
  {
    float w0 = vals[v];
    uint4 d = *(const uint4*)(X1 + myoff);
    float f[8]; bfunpack8(d, f);
    #pragma unroll
    for (int j = 0; j < 8; ++j) a[j] = w0 * f[j];
  }
  #pragma unroll
  for (int jj = 0; jj < 5; ++jj) {
    const int cj[4] = {c4[jj].x, c4[jj].y, c4[jj].z, c4[jj].w};
    const float wj[4] = {w4[jj].x, w4[jj].y, w4[jj].z, w4[jj].w};
    #pragma unroll
    for (int e = 0; e < 4; ++e) {
      uint4 d = *(const uint4*)(plane + (size_t)cj[e] * 32 + ch0);
      float f[8]; bfunpack8(d, f);
      float w = wj[e];
      #pragma unroll
      for (int j = 0; j < 8; ++j) a[j] = fmaf(f[j], w, a[j]);
    }
  }
  uint4 tv = *(const uint4*)(T1 + myoff);
  float f[8]; bfunpack8(tv, f);
  float h[8];
  #pragma unroll
  for (int j = 0; j < 8; ++j) {
    float y = fmaf(f[j], scS[chg + j], shS[chg + j]);
    h[j] = y > 0.f ? y : 0.f;
  }
  uint4 o;
  o.x = packbf(2.f * a[0] - h[0], 2.f * a[1] - h[1]);
  o.y = packbf(2.f * a[2] - h[2], 2.f * a[3] - h[3]);
  o.z = packbf(2.f * a[4] - h[4], 2.f * a[5] - h[5]);
  o.w = packbf(2.f * a[6] - h[6], 2.f * a[7] - h[7]);
  *(uint4*)(X2out + myoff) = o;
}

// ===== GEMM2: t2 = h1@W2[0] + x1@W2[1] + x2@W2[2] + b2 =====================
// All 3 B in LDS (27.6KB); A-frags direct from global per wave; 1 barrier.
#define LDB2 72
__global__ __launch_bounds__(256) void gemm2(const unsigned short* __restrict__ T1,
    const unsigned short* __restrict__ X1, const unsigned short* __restrict__ X2,
    const float* __restrict__ st1, const float* __restrict__ g1,
    const float* __restrict__ be1, const float* __restrict__ W,
    const float* __restrict__ bias, unsigned short* __restrict__ Y,
    float* __restrict__ st2) {
  __shared__ unsigned short Bs[3 * 64 * LDB2];
  __shared__ float sred[128];
  __shared__ float scS[64], shS[64];
  int t = threadIdx.x;
  int row0 = blockIdx.x * 128;
  int b = (row0 >= VN) ? 1 : 0;
  int b2 = b * 2;
  int vb0 = row0 - b * VN;
  if (t < 128) sred[t] = 0.f;
  if (t < 64) {
    float mean = st1[t] * (1.f / MROWS);
    float var = st1[64 + t] * (1.f / MROWS) - mean * mean;
    float sc = g1[t] * rsqrtf(var + BN_EPS);
    scS[t] = sc; shS[t] = be1[t] - mean * sc;
  }
  #pragma unroll
  for (int c = 0; c < 48; ++c) {
    int f = c * 256 + t;                     // 12288 = 3*64*64
    int term = f >> 12, rem = f & 4095;
    int k = rem >> 6, n = rem & 63;
    Bs[term * 64 * LDB2 + n * LDB2 + k] = f2bf(W[f]);
  }
  __syncthreads();
  int lane = t & 63, wv = t >> 6;
  int lr = lane & 15, q = lane >> 4;
  float bv4[4];
  #pragma unroll
  for (int nt = 0; nt < 4; ++nt) bv4[nt] = bias[nt * 16 + lr];
  float sc8[8], sh8[8];
  #pragma unroll
  for (int kh = 0; kh < 2; ++kh)
    #pragma unroll
    for (int j = 0; j < 4; ++j) {
      sc8[kh * 4 + j] = scS[kh * 32 + q * 8 + j + 0];
      sh8[kh * 4 + j] = shS[kh * 32 + q * 8 + j + 0];
    }
  // NOTE: need all 8 per kh; redo properly below in-loop via scS index.
  float s4[4] = {0.f, 0.f, 0.f, 0.f}, s24[4] = {0.f, 0.f, 0.f, 0.f};
  #pragma unroll
  for (int tile = 0; tile < 2; ++tile) {
    int vrow = vb0 + wv * 32 + tile * 16 + lr;
    bf16x8 af0[2], af1[2], af2[2];
    #pragma unroll
    for (int kh = 0; kh < 2; ++kh) {
      size_t off = ((size_t)(b2 + kh) * VN + vrow) * 32 + q * 8;
      uint4 d0 = *(const uint4*)(T1 + off);
      float f8[8]; bfunpack8(d0, f8);
      #pragma unroll
      for (int j = 0; j < 8; ++j) {
        float y = fmaf(f8[j], scS[kh * 32 + q * 8 + j], shS[kh * 32 + q * 8 + j]);
        f8[j] = y > 0.f ? y : 0.f;
      }
      uint4 u = make_uint4(packbf(f8[0], f8[1]), packbf(f8[2], f8[3]),
                           packbf(f8[4], f8[5]), packbf(f8[6], f8[7]));
      af0[kh] = __builtin_bit_cast(bf16x8, u);
      af1[kh] = __builtin_bit_cast(bf16x8, *(const uint4*)(X1 + off));
      af2[kh] = __builtin_bit_cast(bf16x8, *(const uint4*)(X2 + off));
    }
    floatx4 acc[4];
    #pragma unroll
    for (int nt = 0; nt < 4; ++nt) acc[nt] = (floatx4)(0.f);
    #pragma unroll
    for (int kh = 0; kh < 2; ++kh)
      #pragma unroll
      for (int nt = 0; nt < 4; ++nt) {
        int bo = (nt * 16 + lr) * LDB2 + kh * 32 + q * 8;
        acc[nt] = __builtin_amdgcn_mfma_f32_16x16x32_bf16(
            af0[kh], *(const bf16x8*)(&Bs[bo]), acc[nt], 0, 0, 0);
        acc[nt] = __builtin_amdgcn_mfma_f32_16x16x32_bf16(
            af1[kh], *(const bf16x8*)(&Bs[64 * LDB2 + bo]), acc[nt], 0, 0, 0);
        acc[nt] = __builtin_amdgcn_mfma_f32_16x16x32_bf16(
            af2[kh], *(const bf16x8*)(&Bs[2 * 64 * LDB2 + bo]), acc[nt], 0, 0, 0);
      }
    int vbase = vb0 + wv * 32 + tile * 16 + q * 4;
    #pragma unroll
    for (int nt = 0; nt < 4; ++nt) {
      int col = nt * 16 + lr;
      size_t sub = (size_t)(b2 + (col >> 5)) * VN;
      #pragma unroll
      for (int r = 0; r < 4; ++r) {
        float y = acc[nt][r] + bv4[nt];
        s4[nt] += y; s24[nt] += y * y;
        Y[(sub + vbase + r) * 32 + (col & 31)] = f2bf(y);
      }
    }
  }
  #pragma unroll
  for (int nt = 0; nt < 4; ++nt) {
    int col = nt * 16 + lr;
    atomicAdd(&sred[col], s4[nt]);
    atomicAdd(&sred[64 + col], s24[nt]);
  }
  __syncthreads();
  if (t < 128) atomicAdd(&st2[t], sred[t]);
}

// ====== GEMM3: t3 = h2 @ W3 + b3 (N=128); A direct from global =============
__global__ __launch_bounds__(256) void gemm3(const unsigned short* __restrict__ T2,
    const float* __restrict__ W, const float* __restrict__ bias,
    const float* __restrict__ st2, const float* __restrict__ g2,
    const float* __restrict__ be2, unsigned short* __restrict__ Y,
    float* __restrict__ st3) {
  __shared__ unsigned short Bs[128 * LDB2];    // B^T [n=128][k=64]
  __shared__ float sred[256];
  __shared__ float scS[64], shS[64];
  int t = threadIdx.x;
  int row0 = blockIdx.x * 128;
  int b = (row0 >= VN) ? 1 : 0;
  int b2 = b * 2;
  int vb0 = row0 - b * VN;
  sred[t] = 0.f;
  if (t < 64) {
    float mean = st2[t] * (1.f / MROWS);
    float var = st2[64 + t] * (1.f / MROWS) - mean * mean;
    float sc = g2[t] * rsqrtf(var + BN_EPS);
    scS[t] = sc; shS[t] = be2[t] - mean * sc;
  }
  #pragma unroll
  for (int c = 0; c < 32; ++c) {
    int f = c * 256 + t;                     // 8192 = 64*128
    int k = f >> 7, n = f & 127;
    Bs[n * LDB2 + k] = f2bf(W[k * 128 + n]);
  }
  __syncthreads();
  int lane = t & 63, wv = t >> 6;
  int lr = lane & 15, q = lane >> 4;
  float bv8[8];
  #pragma unroll
  for (int nt = 0; nt < 8; ++nt) bv8[nt] = bias[nt * 16 + lr];
  float s8[8] = {0.f,0.f,0.f,0.f,0.f,0.f,0.f,0.f};
  float s28[8] = {0.f,0.f,0.f,0.f,0.f,0.f,0.f,0.f};
  #pragma unroll
  for (int tile = 0; tile < 2; ++tile) {
    int vrow = vb0 + wv * 32 + tile * 16 + lr;
    bf16x8 af[2];
    #pragma unroll
    for (int kh = 0; kh < 2; ++kh) {
      uint4 d = *(const uint4*)(T2 + ((size_t)(b2 + kh) * VN + vrow) * 32 + q * 8);
      float f8[8]; bfunpack8(d, f8);
      #pragma unroll
      for (int j = 0; j < 8; ++j) {
        float y = fmaf(f8[j], scS[kh * 32 + q * 8 + j], shS[kh * 32 + q * 8 + j]);
        f8[j] = y > 0.f ? y : 0.f;
      }
      uint4 u = make_uint4(packbf(f8[0], f8[1]), packbf(f8[2], f8[3]),
                           packbf(f8[4], f8[5]), packbf(f8[6], f8[7]));
      af[kh] = __builtin_bit_cast(bf16x8, u);
    }
    floatx4 acc[8];
    #pragma unroll
    for (int nt = 0; nt < 8; ++nt) acc[nt] = (floatx4)(0.f);
    #pragma unroll
    for (int kh = 0; kh < 2; ++kh)
      #pragma unroll
      for (int nt = 0; nt < 8; ++nt) {
        bf16x8 bfr = *(const bf16x8*)(&Bs[(nt * 16 + lr) * LDB2 + kh * 32 + q * 8]);
        acc[nt] = __builtin_amdgcn_mfma_f32_16x16x32_bf16(af[kh], bfr, acc[nt], 0, 0, 0);
      }
    int rbase = row0 + wv * 32 + tile * 16 + q * 4;
    #pragma unroll
    for (int nt = 0; nt < 8; ++nt) {
      int col = nt * 16 + lr;
      #pragma unroll
      for (int r = 0; r < 4; ++r) {
        float y = acc[nt][r] + bv8[nt];
        s8[nt] += y; s28[nt] += y * y;
        Y[(size_t)(rbase + r) * 128 + col] = f2bf(y);
      }
    }
  }
  #pragma unroll
  for (int nt = 0; nt < 8; ++nt) {
    int col = nt * 16 + lr;
    atomicAdd(&sred[col], s8[nt]);
    atomicAdd(&sred[128 + col], s28[nt]);
  }
  __syncthreads();
  atomicAdd(&st3[t], sred[t]);
}

// --------- final: out = relu(bn3(t3)) fp32; bn3 finalized inline -----------
__global__ __launch_bounds__(256) void bn_final(const unsigned short* __restrict__ T,
    float* __restrict__ Y, const float* __restrict__ st3,
    const float* __restrict__ gamma, const float* __restrict__ beta) {
  __shared__ float scS[128], shS[128];
  int t = threadIdx.x;
  if (t < 128) {
    float mean = st3[t] * (1.f / MROWS);
    float var = st3[128 + t] * (1.f / MROWS) - mean * mean;
    float sc = gamma[t] * rsqrtf(var + BN_EPS);
    scS[t] = sc;
    shS[t] = beta[t] - mean * sc;
  }
  __syncthreads();
  size_t i4 = ((size_t)blockIdx.x * 256 + t) * 4;
  int c0 = (int)(i4 & 127);
  ushort4 tv = *(const ushort4*)(T + i4);
  unsigned short sv[4] = {tv.x, tv.y, tv.z, tv.w};
  float ov[4];
  #pragma unroll
  for (int j = 0; j < 4; ++j) {
    int c = c0 + j;
    float y = fmaf(bf2f(sv[j]), scS[c], shS[c]);
    ov[j] = y > 0.f ? y : 0.f;
  }
  *(float4*)(Y + i4) = make_float4(ov[0], ov[1], ov[2], ov[3]);
}

extern "C" void kernel_launch(void* const* d_in, const int* in_sizes, int n_in,
                              void* d_out, int out_size, void* d_ws, size_t ws_size,
                              hipStream_t stream) {
  const float* x    = (const float*)d_in[0];
  const int*   cols = (const int*)  d_in[2];
  const float* vals = (const float*)d_in[3];
  const float* W1   = (const float*)d_in[4];
  const float* b1   = (const float*)d_in[5];
  const float* g1   = (const float*)d_in[6];
  const float* be1  = (const float*)d_in[7];
  const float* W2   = (const float*)d_in[8];
  const float* b2   = (const float*)d_in[9];
  const float* g2   = (const float*)d_in[10];
  const float* be2  = (const float*)d_in[11];
  const float* W3   = (const float*)d_in[12];
  const float* b3   = (const float*)d_in[13];
  const float* g3   = (const float*)d_in[14];
  const float* be3  = (const float*)d_in[15];
  float* out = (float*)d_out;

  const size_t PL = (size_t)MROWS * 64;          // plane elements
  unsigned short* P0 = (unsigned short*)d_ws;    // t1, then t2 (band/wave-local in-place)
  unsigned short* P1 = P0 + PL;                  // x1
  unsigned short* P2 = P1 + PL;                  // x2
  unsigned short* P3 = P2 + PL;                  // t3 [MROWS,128]
  float* st1 = (float*)(P3 + 2 * PL);            // 128
  float* st2 = st1 + 128;                        // 128
  float* st3 = st2 + 128;                        // 256

  hipMemsetAsync(st1, 0, 512 * sizeof(float), stream);

  dim3 blk(256);
  int rowb = MROWS / 128;                        // 768
  int spmm_blocks = 3072;                        // 64 rows x 4 combos
  int ap128_blocks = (int)(PL * 2 / 4 / 256);    // 12288

  // Layer 1 (stats via atomics; bn1 applied by consumers)
  gemm1<<<rowb, blk, 0, stream>>>(x, W1, b1, P0, st1);

  // Layer 2: combo-pinned spmm kernels; gemm2 wave-streaming
  spmm1<<<spmm_blocks, blk, 0, stream>>>(P0, cols, vals, st1, g1, be1, P1);
  spmm2<<<spmm_blocks, blk, 0, stream>>>(P1, P0, cols, vals, st1, g1, be1, P2);
  gemm2<<<rowb, blk, 0, stream>>>(P0, P1, P2, st1, g1, be1, W2, b2, P0, st2);

  // Layer 3
  gemm3<<<rowb, blk, 0, stream>>>(P0, W3, b3, st2, g2, be2, P3, st3);
  bn_final<<<ap128_blocks, blk, 0, stream>>>(P3, out, st3, g3, be3);
}